// Round 5
// baseline (786.819 us; speedup 1.0000x reference)
//
#include <hip/hip_runtime.h>

typedef __attribute__((ext_vector_type(8))) short bf16x8;
typedef __attribute__((ext_vector_type(4))) float f32x4;

#define NBLK   16          // nodes per tile
#define DIMF   1152        // floats per node row
#define NTILE  6250        // 100000 / 16, exact
#define GRIDSZ 512         // exactly 2 blocks/CU resident, 12-13 tiles each
#define ROWU   1160        // padded ushort stride per node row (2320 B -> +4 dword banks/row)

// round-to-nearest-even f32 -> bf16 bits (no NaNs in this data)
static __device__ __forceinline__ unsigned short f2bf(float f) {
    unsigned int u = __builtin_bit_cast(unsigned int, f);
    return (unsigned short)((u + 0x7FFFu + ((u >> 16) & 1u)) >> 16);
}

__global__ __launch_bounds__(512, 2)
void seglin_kernel(const float* __restrict__ x, const float* __restrict__ w,
                   const float* __restrict__ b, float* __restrict__ out) {
    // LDS layout: per node, 9 planes of 128 u-contiguous bf16:
    //   plane 0 (off 0)              = seg0
    //   planes 1..3 (off 128+i*128)  = seg1, i = 0..2
    //   planes 4..8 (off 512+i*128)  = seg2, i = 0..4
    __shared__ unsigned short xs[2][NBLK][ROWU];

    const int tid  = threadIdx.x;
    const int wv   = tid >> 6;        // wave -> v rows [16*wv, 16*wv+16)
    const int lane = tid & 63;
    const int lq   = lane & 15;       // node col n (B); A row v_local (W frags)
    const int lg   = lane >> 4;       // k-group 0..3
    const int v0   = wv * 16;

    // staging mapping: thread -> (node, 4-u chunk)
    const int sn = tid >> 5;          // node 0..15
    const int st = tid & 31;          // u-chunk 0..31 (u = 4*st..4*st+3)

    const float pw = 0.08838834764831845f;  // 128^-0.5, folded into W

    // ---- hoist A = pw * W^T fragments into registers (once per block) ----
    bf16x8 wf[3][4];
    const int woff[3] = {0, 16384, 32768};
    #pragma unroll
    for (int s = 0; s < 3; ++s)
        #pragma unroll
        for (int t = 0; t < 4; ++t) {
            bf16x8 f;
            #pragma unroll
            for (int e = 0; e < 8; ++e) {
                int u = 32 * t + lg * 8 + e;
                f[e] = (short)f2bf(pw * w[woff[s] + u * 128 + v0 + lq]);
            }
            wf[s][t] = f;
        }

    float biasr[4];
    #pragma unroll
    for (int e = 0; e < 4; ++e) biasr[e] = b[v0 + lg * 4 + e];

    float4 g0, g1[3], g2[5];   // per-thread staged 36 floats

#define STAGE_LOAD(TILE) do {                                                   \
        const float* src = x + ((long)(TILE) * NBLK + sn) * DIMF;               \
        g0    = *reinterpret_cast<const float4*>(src + 4 * st);                 \
        g1[0] = *reinterpret_cast<const float4*>(src + 128 + 12 * st);          \
        g1[1] = *reinterpret_cast<const float4*>(src + 128 + 12 * st + 4);      \
        g1[2] = *reinterpret_cast<const float4*>(src + 128 + 12 * st + 8);      \
        g2[0] = *reinterpret_cast<const float4*>(src + 512 + 20 * st);          \
        g2[1] = *reinterpret_cast<const float4*>(src + 512 + 20 * st + 4);      \
        g2[2] = *reinterpret_cast<const float4*>(src + 512 + 20 * st + 8);      \
        g2[3] = *reinterpret_cast<const float4*>(src + 512 + 20 * st + 12);     \
        g2[4] = *reinterpret_cast<const float4*>(src + 512 + 20 * st + 16);     \
    } while (0)

    // seg1 value at plane i, pos u=4st+e is src[128 + 12st + 3e + i] = f1[3e+i]
    // seg2 value at plane i, pos u=4st+e is src[512 + 20st + 5e + i] = f2[5e+i]
#define STAGE_WRITE(BUF) do {                                                   \
        unsigned short* dst = &xs[BUF][sn][0];                                  \
        { ushort4 h;                                                            \
          h.x = f2bf(g0.x); h.y = f2bf(g0.y); h.z = f2bf(g0.z); h.w = f2bf(g0.w); \
          *reinterpret_cast<ushort4*>(dst + 4 * st) = h; }                      \
        float f1[12], f2[20];                                                   \
        f1[0]=g1[0].x; f1[1]=g1[0].y; f1[2]=g1[0].z; f1[3]=g1[0].w;             \
        f1[4]=g1[1].x; f1[5]=g1[1].y; f1[6]=g1[1].z; f1[7]=g1[1].w;             \
        f1[8]=g1[2].x; f1[9]=g1[2].y; f1[10]=g1[2].z; f1[11]=g1[2].w;           \
        _Pragma("unroll")                                                       \
        for (int i = 0; i < 3; ++i) {                                           \
            ushort4 h;                                                          \
            h.x = f2bf(f1[0 + i]); h.y = f2bf(f1[3 + i]);                       \
            h.z = f2bf(f1[6 + i]); h.w = f2bf(f1[9 + i]);                       \
            *reinterpret_cast<ushort4*>(dst + 128 + (i << 7) + 4 * st) = h;     \
        }                                                                       \
        f2[0]=g2[0].x; f2[1]=g2[0].y; f2[2]=g2[0].z; f2[3]=g2[0].w;             \
        f2[4]=g2[1].x; f2[5]=g2[1].y; f2[6]=g2[1].z; f2[7]=g2[1].w;             \
        f2[8]=g2[2].x; f2[9]=g2[2].y; f2[10]=g2[2].z; f2[11]=g2[2].w;           \
        f2[12]=g2[3].x; f2[13]=g2[3].y; f2[14]=g2[3].z; f2[15]=g2[3].w;         \
        f2[16]=g2[4].x; f2[17]=g2[4].y; f2[18]=g2[4].z; f2[19]=g2[4].w;         \
        _Pragma("unroll")                                                       \
        for (int i = 0; i < 5; ++i) {                                           \
            ushort4 h;                                                          \
            h.x = f2bf(f2[0 + i]);  h.y = f2bf(f2[5 + i]);                      \
            h.z = f2bf(f2[10 + i]); h.w = f2bf(f2[15 + i]);                     \
        *reinterpret_cast<ushort4*>(dst + 512 + (i << 7) + 4 * st) = h;         \
        }                                                                       \
    } while (0)

    // ---- prologue: stage first tile into buffer 0 (full barrier, once) ----
    long tile = blockIdx.x;
    STAGE_LOAD(tile);
    STAGE_WRITE(0);
    __syncthreads();

    int cur = 0;
    for (; tile < NTILE; tile += GRIDSZ) {
        const bool has_next = (tile + GRIDSZ) < NTILE;

        // T14: issue next tile's global loads early; latency hides under compute
        if (has_next) STAGE_LOAD(tile + GRIDSZ);

        // ---- compute from xs[cur]: every B-frag is one ds_read_b128 ----
        f32x4 acc[9];
        #pragma unroll
        for (int q = 0; q < 9; ++q) {
            f32x4 z = {0.f, 0.f, 0.f, 0.f};
            acc[q] = z;
        }

        const unsigned short* row = &xs[cur][lq][0];
        #pragma unroll
        for (int t = 0; t < 4; ++t) {
            const int u0 = 32 * t + lg * 8;
            #pragma unroll
            for (int q = 0; q < 9; ++q) {
                const int s = (q == 0) ? 0 : (q < 4 ? 1 : 2);
                bf16x8 bf = *reinterpret_cast<const bf16x8*>(row + (q << 7) + u0);
                acc[q] = __builtin_amdgcn_mfma_f32_16x16x32_bf16(wf[s][t], bf, acc[q], 0, 0, 0);
            }
        }

        // ---- epilogue: 9 aligned nontemporal float4 stores (out is write-once) ----
        {
            float* orow = out + (tile * NBLK + lq) * (long)DIMF;
            const int vb = v0 + lg * 4;
            f32x4 o0;
            o0[0] = acc[0][0] + biasr[0];
            o0[1] = acc[0][1] + biasr[1];
            o0[2] = acc[0][2] + biasr[2];
            o0[3] = acc[0][3] + biasr[3];
            __builtin_nontemporal_store(o0, reinterpret_cast<f32x4*>(orow + vb));
            float* p1 = orow + 128 + 3 * vb;    // 12 consecutive: p=3e+i -> acc[1+p%3][p/3]
            #pragma unroll
            for (int k = 0; k < 3; ++k) {
                f32x4 o;
                o[0] = acc[1 + ((4 * k + 0) % 3)][(4 * k + 0) / 3];
                o[1] = acc[1 + ((4 * k + 1) % 3)][(4 * k + 1) / 3];
                o[2] = acc[1 + ((4 * k + 2) % 3)][(4 * k + 2) / 3];
                o[3] = acc[1 + ((4 * k + 3) % 3)][(4 * k + 3) / 3];
                __builtin_nontemporal_store(o, reinterpret_cast<f32x4*>(p1 + 4 * k));
            }
            float* p2 = orow + 512 + 5 * vb;    // 20 consecutive: p=5e+i -> acc[4+p%5][p/5]
            #pragma unroll
            for (int k = 0; k < 5; ++k) {
                f32x4 o;
                o[0] = acc[4 + ((4 * k + 0) % 5)][(4 * k + 0) / 5];
                o[1] = acc[4 + ((4 * k + 1) % 5)][(4 * k + 1) / 5];
                o[2] = acc[4 + ((4 * k + 2) % 5)][(4 * k + 2) / 5];
                o[3] = acc[4 + ((4 * k + 3) % 5)][(4 * k + 3) / 5];
                __builtin_nontemporal_store(o, reinterpret_cast<f32x4*>(p2 + 4 * k));
            }
        }

        // ---- convert + write next tile into the other buffer ----
        if (has_next) STAGE_WRITE(cur ^ 1);

        // Relaxed barrier: only LDS writes must be visible (lgkmcnt(0)).
        // Global stores/loads keep draining across the next tile's compute
        // (counted-vmcnt discipline: never vmcnt(0) in the main loop).
        asm volatile("s_waitcnt lgkmcnt(0)\n\ts_barrier" ::: "memory");
        cur ^= 1;
    }
#undef STAGE_LOAD
#undef STAGE_WRITE
}

extern "C" void kernel_launch(void* const* d_in, const int* in_sizes, int n_in,
                              void* d_out, int out_size, void* d_ws, size_t ws_size,
                              hipStream_t stream) {
    const float* x = (const float*)d_in[0];
    const float* w = (const float*)d_in[1];
    const float* b = (const float*)d_in[2];
    float* outp = (float*)d_out;
    seglin_kernel<<<dim3(GRIDSZ), dim3(512), 0, stream>>>(x, w, b, outp);
}

// Round 6
// 187.897 us; speedup vs baseline: 4.1875x; 4.1875x over previous
//
#include <hip/hip_runtime.h>

typedef __attribute__((ext_vector_type(8))) short bf16x8;
typedef __attribute__((ext_vector_type(4))) float f32x4;

#define NBLK   16          // nodes per tile
#define DIMF   1152        // floats per node row
#define NTILE  6250        // 100000 / 16, exact
#define GRIDSZ 512         // exactly 2 blocks/CU resident, 12-13 tiles each
#define ROWU   1160        // padded ushort stride per node row (2320 B -> +4 dword banks/row)

// round-to-nearest-even f32 -> bf16 bits (no NaNs in this data)
static __device__ __forceinline__ unsigned short f2bf(float f) {
    unsigned int u = __builtin_bit_cast(unsigned int, f);
    return (unsigned short)((u + 0x7FFFu + ((u >> 16) & 1u)) >> 16);
}

__global__ __launch_bounds__(512, 2)
void seglin_kernel(const float* __restrict__ x, const float* __restrict__ w,
                   const float* __restrict__ b, float* __restrict__ out) {
    // LDS layout: per node, 9 planes of 128 u-contiguous bf16:
    //   plane 0 (off 0)              = seg0
    //   planes 1..3 (off 128+i*128)  = seg1, i = 0..2
    //   planes 4..8 (off 512+i*128)  = seg2, i = 0..4
    __shared__ unsigned short xs[2][NBLK][ROWU];

    const int tid  = threadIdx.x;
    const int wv   = tid >> 6;        // wave -> v rows [16*wv, 16*wv+16)
    const int lane = tid & 63;
    const int lq   = lane & 15;       // node col n (B); A row v_local (W frags)
    const int lg   = lane >> 4;       // k-group 0..3
    const int v0   = wv * 16;

    // staging mapping: thread -> (node, 4-u chunk)
    const int sn = tid >> 5;          // node 0..15
    const int st = tid & 31;          // u-chunk 0..31 (u = 4*st..4*st+3)

    const float pw = 0.08838834764831845f;  // 128^-0.5, folded into W

    // ---- hoist A = pw * W^T fragments into registers (once per block) ----
    bf16x8 wf[3][4];
    const int woff[3] = {0, 16384, 32768};
    #pragma unroll
    for (int s = 0; s < 3; ++s)
        #pragma unroll
        for (int t = 0; t < 4; ++t) {
            bf16x8 f;
            #pragma unroll
            for (int e = 0; e < 8; ++e) {
                int u = 32 * t + lg * 8 + e;
                f[e] = (short)f2bf(pw * w[woff[s] + u * 128 + v0 + lq]);
            }
            wf[s][t] = f;
        }

    float biasr[4];
    #pragma unroll
    for (int e = 0; e < 4; ++e) biasr[e] = b[v0 + lg * 4 + e];

    float4 g0, g1[3], g2[5];   // per-thread staged 36 floats

#define STAGE_LOAD(TILE) do {                                                   \
        const float* src = x + ((long)(TILE) * NBLK + sn) * DIMF;               \
        g0    = *reinterpret_cast<const float4*>(src + 4 * st);                 \
        g1[0] = *reinterpret_cast<const float4*>(src + 128 + 12 * st);          \
        g1[1] = *reinterpret_cast<const float4*>(src + 128 + 12 * st + 4);      \
        g1[2] = *reinterpret_cast<const float4*>(src + 128 + 12 * st + 8);      \
        g2[0] = *reinterpret_cast<const float4*>(src + 512 + 20 * st);          \
        g2[1] = *reinterpret_cast<const float4*>(src + 512 + 20 * st + 4);      \
        g2[2] = *reinterpret_cast<const float4*>(src + 512 + 20 * st + 8);      \
        g2[3] = *reinterpret_cast<const float4*>(src + 512 + 20 * st + 12);     \
        g2[4] = *reinterpret_cast<const float4*>(src + 512 + 20 * st + 16);     \
    } while (0)

    // seg1 value at plane i, pos u=4st+e is src[128 + 12st + 3e + i] = f1[3e+i]
    // seg2 value at plane i, pos u=4st+e is src[512 + 20st + 5e + i] = f2[5e+i]
#define STAGE_WRITE(BUF) do {                                                   \
        unsigned short* dst = &xs[BUF][sn][0];                                  \
        { ushort4 h;                                                            \
          h.x = f2bf(g0.x); h.y = f2bf(g0.y); h.z = f2bf(g0.z); h.w = f2bf(g0.w); \
          *reinterpret_cast<ushort4*>(dst + 4 * st) = h; }                      \
        float f1[12], f2[20];                                                   \
        f1[0]=g1[0].x; f1[1]=g1[0].y; f1[2]=g1[0].z; f1[3]=g1[0].w;             \
        f1[4]=g1[1].x; f1[5]=g1[1].y; f1[6]=g1[1].z; f1[7]=g1[1].w;             \
        f1[8]=g1[2].x; f1[9]=g1[2].y; f1[10]=g1[2].z; f1[11]=g1[2].w;           \
        _Pragma("unroll")                                                       \
        for (int i = 0; i < 3; ++i) {                                           \
            ushort4 h;                                                          \
            h.x = f2bf(f1[0 + i]); h.y = f2bf(f1[3 + i]);                       \
            h.z = f2bf(f1[6 + i]); h.w = f2bf(f1[9 + i]);                       \
            *reinterpret_cast<ushort4*>(dst + 128 + (i << 7) + 4 * st) = h;     \
        }                                                                       \
        f2[0]=g2[0].x; f2[1]=g2[0].y; f2[2]=g2[0].z; f2[3]=g2[0].w;             \
        f2[4]=g2[1].x; f2[5]=g2[1].y; f2[6]=g2[1].z; f2[7]=g2[1].w;             \
        f2[8]=g2[2].x; f2[9]=g2[2].y; f2[10]=g2[2].z; f2[11]=g2[2].w;           \
        f2[12]=g2[3].x; f2[13]=g2[3].y; f2[14]=g2[3].z; f2[15]=g2[3].w;         \
        f2[16]=g2[4].x; f2[17]=g2[4].y; f2[18]=g2[4].z; f2[19]=g2[4].w;         \
        _Pragma("unroll")                                                       \
        for (int i = 0; i < 5; ++i) {                                           \
            ushort4 h;                                                          \
            h.x = f2bf(f2[0 + i]);  h.y = f2bf(f2[5 + i]);                      \
            h.z = f2bf(f2[10 + i]); h.w = f2bf(f2[15 + i]);                     \
            *reinterpret_cast<ushort4*>(dst + 512 + (i << 7) + 4 * st) = h;     \
        }                                                                       \
    } while (0)

    // ---- prologue: stage first tile into buffer 0 (full barrier, once) ----
    long tile = blockIdx.x;
    STAGE_LOAD(tile);
    STAGE_WRITE(0);
    __syncthreads();

    int cur = 0;
    for (; tile < NTILE; tile += GRIDSZ) {
        const bool has_next = (tile + GRIDSZ) < NTILE;

        // T14: issue next tile's global loads early; latency hides under compute
        if (has_next) STAGE_LOAD(tile + GRIDSZ);

        // ---- compute from xs[cur]: every B-frag is one ds_read_b128 ----
        f32x4 acc[9];
        #pragma unroll
        for (int q = 0; q < 9; ++q) {
            f32x4 z = {0.f, 0.f, 0.f, 0.f};
            acc[q] = z;
        }

        const unsigned short* row = &xs[cur][lq][0];
        #pragma unroll
        for (int t = 0; t < 4; ++t) {
            const int u0 = 32 * t + lg * 8;
            #pragma unroll
            for (int q = 0; q < 9; ++q) {
                const int s = (q == 0) ? 0 : (q < 4 ? 1 : 2);
                bf16x8 bf = *reinterpret_cast<const bf16x8*>(row + (q << 7) + u0);
                acc[q] = __builtin_amdgcn_mfma_f32_16x16x32_bf16(wf[s][t], bf, acc[q], 0, 0, 0);
            }
        }

        // ---- epilogue: 9 aligned float4 stores (plain: L2 write-back combines
        //      16B granules into full lines; nt stores amplified WRITE 2.7x) ----
        {
            float* orow = out + (tile * NBLK + lq) * (long)DIMF;
            const int vb = v0 + lg * 4;
            float4 o0;
            o0.x = acc[0][0] + biasr[0];
            o0.y = acc[0][1] + biasr[1];
            o0.z = acc[0][2] + biasr[2];
            o0.w = acc[0][3] + biasr[3];
            *reinterpret_cast<float4*>(orow + vb) = o0;
            float* p1 = orow + 128 + 3 * vb;    // 12 consecutive: p=3e+i -> acc[1+p%3][p/3]
            #pragma unroll
            for (int k = 0; k < 3; ++k) {
                float4 o;
                o.x = acc[1 + ((4 * k + 0) % 3)][(4 * k + 0) / 3];
                o.y = acc[1 + ((4 * k + 1) % 3)][(4 * k + 1) / 3];
                o.z = acc[1 + ((4 * k + 2) % 3)][(4 * k + 2) / 3];
                o.w = acc[1 + ((4 * k + 3) % 3)][(4 * k + 3) / 3];
                *reinterpret_cast<float4*>(p1 + 4 * k) = o;
            }
            float* p2 = orow + 512 + 5 * vb;    // 20 consecutive: p=5e+i -> acc[4+p%5][p/5]
            #pragma unroll
            for (int k = 0; k < 5; ++k) {
                float4 o;
                o.x = acc[4 + ((4 * k + 0) % 5)][(4 * k + 0) / 5];
                o.y = acc[4 + ((4 * k + 1) % 5)][(4 * k + 1) / 5];
                o.z = acc[4 + ((4 * k + 2) % 5)][(4 * k + 2) / 5];
                o.w = acc[4 + ((4 * k + 3) % 5)][(4 * k + 3) / 5];
                *reinterpret_cast<float4*>(p2 + 4 * k) = o;
            }
        }

        // ---- convert + write next tile into the other buffer ----
        if (has_next) STAGE_WRITE(cur ^ 1);

        // Relaxed barrier: only LDS writes must be visible (lgkmcnt(0)).
        // Global stores/loads keep draining across the next tile's compute
        // (counted-vmcnt discipline: never vmcnt(0) in the main loop).
        asm volatile("s_waitcnt lgkmcnt(0)\n\ts_barrier" ::: "memory");
        cur ^= 1;
    }
#undef STAGE_LOAD
#undef STAGE_WRITE
}

extern "C" void kernel_launch(void* const* d_in, const int* in_sizes, int n_in,
                              void* d_out, int out_size, void* d_ws, size_t ws_size,
                              hipStream_t stream) {
    const float* x = (const float*)d_in[0];
    const float* w = (const float*)d_in[1];
    const float* b = (const float*)d_in[2];
    float* outp = (float*)d_out;
    seglin_kernel<<<dim3(GRIDSZ), dim3(512), 0, stream>>>(x, w, b, outp);
}

// Round 7
// 187.210 us; speedup vs baseline: 4.2029x; 1.0037x over previous
//
#include <hip/hip_runtime.h>

typedef __attribute__((ext_vector_type(8))) short bf16x8;
typedef __attribute__((ext_vector_type(4))) float f32x4;

#define NBLK   16          // nodes per tile
#define DIMF   1152        // floats per node row
#define NTILE  6250        // 100000 / 16, exact
#define GRIDSZ 512         // exactly 2 blocks/CU resident, 12-13 tiles each
#define ROWU   1160        // padded ushort stride per node row (2320 B -> +4 dword banks/row)

// round-to-nearest-even f32 -> bf16 bits (no NaNs in this data)
static __device__ __forceinline__ unsigned short f2bf(float f) {
    unsigned int u = __builtin_bit_cast(unsigned int, f);
    return (unsigned short)((u + 0x7FFFu + ((u >> 16) & 1u)) >> 16);
}

__global__ __launch_bounds__(512, 2)
void seglin_kernel(const float* __restrict__ x, const float* __restrict__ w,
                   const float* __restrict__ b, float* __restrict__ out) {
    // LDS layout: per node, 9 planes of 128 u-contiguous bf16:
    //   plane 0 (off 0)              = seg0
    //   planes 1..3 (off 128+i*128)  = seg1, i = 0..2
    //   planes 4..8 (off 512+i*128)  = seg2, i = 0..4
    __shared__ unsigned short xs[2][NBLK][ROWU];

    const int tid  = threadIdx.x;
    const int wv   = tid >> 6;        // wave -> v rows [16*wv, 16*wv+16)
    const int lane = tid & 63;
    const int lq   = lane & 15;       // node col n (B); A row v_local (W frags)
    const int lg   = lane >> 4;       // k-group 0..3
    const int v0   = wv * 16;

    // staging mapping: thread -> (node, 4-u chunk)
    const int sn = tid >> 5;          // node 0..15
    const int st = tid & 31;          // u-chunk 0..31 (u = 4*st..4*st+3)

    const float pw = 0.08838834764831845f;  // 128^-0.5, folded into W

    // ---- hoist A = pw * W^T fragments into registers (once per block) ----
    bf16x8 wf[3][4];
    const int woff[3] = {0, 16384, 32768};
    #pragma unroll
    for (int s = 0; s < 3; ++s)
        #pragma unroll
        for (int t = 0; t < 4; ++t) {
            bf16x8 f;
            #pragma unroll
            for (int e = 0; e < 8; ++e) {
                int u = 32 * t + lg * 8 + e;
                f[e] = (short)f2bf(pw * w[woff[s] + u * 128 + v0 + lq]);
            }
            wf[s][t] = f;
        }

    float biasr[4];
    #pragma unroll
    for (int e = 0; e < 4; ++e) biasr[e] = b[v0 + lg * 4 + e];

    float4 g0, g1[3], g2[5];   // per-thread staged 36 floats (one tile in flight)

#define STAGE_LOAD(TILE) do {                                                   \
        const float* src = x + ((long)(TILE) * NBLK + sn) * DIMF;               \
        g0    = *reinterpret_cast<const float4*>(src + 4 * st);                 \
        g1[0] = *reinterpret_cast<const float4*>(src + 128 + 12 * st);          \
        g1[1] = *reinterpret_cast<const float4*>(src + 128 + 12 * st + 4);      \
        g1[2] = *reinterpret_cast<const float4*>(src + 128 + 12 * st + 8);      \
        g2[0] = *reinterpret_cast<const float4*>(src + 512 + 20 * st);          \
        g2[1] = *reinterpret_cast<const float4*>(src + 512 + 20 * st + 4);      \
        g2[2] = *reinterpret_cast<const float4*>(src + 512 + 20 * st + 8);      \
        g2[3] = *reinterpret_cast<const float4*>(src + 512 + 20 * st + 12);     \
        g2[4] = *reinterpret_cast<const float4*>(src + 512 + 20 * st + 16);     \
    } while (0)

    // seg1 value at plane i, pos u=4st+e is src[128 + 12st + 3e + i] = f1[3e+i]
    // seg2 value at plane i, pos u=4st+e is src[512 + 20st + 5e + i] = f2[5e+i]
#define STAGE_WRITE(BUF) do {                                                   \
        unsigned short* dst = &xs[BUF][sn][0];                                  \
        { ushort4 h;                                                            \
          h.x = f2bf(g0.x); h.y = f2bf(g0.y); h.z = f2bf(g0.z); h.w = f2bf(g0.w); \
          *reinterpret_cast<ushort4*>(dst + 4 * st) = h; }                      \
        float f1[12], f2[20];                                                   \
        f1[0]=g1[0].x; f1[1]=g1[0].y; f1[2]=g1[0].z; f1[3]=g1[0].w;             \
        f1[4]=g1[1].x; f1[5]=g1[1].y; f1[6]=g1[1].z; f1[7]=g1[1].w;             \
        f1[8]=g1[2].x; f1[9]=g1[2].y; f1[10]=g1[2].z; f1[11]=g1[2].w;           \
        _Pragma("unroll")                                                       \
        for (int i = 0; i < 3; ++i) {                                           \
            ushort4 h;                                                          \
            h.x = f2bf(f1[0 + i]); h.y = f2bf(f1[3 + i]);                       \
            h.z = f2bf(f1[6 + i]); h.w = f2bf(f1[9 + i]);                       \
            *reinterpret_cast<ushort4*>(dst + 128 + (i << 7) + 4 * st) = h;     \
        }                                                                       \
        f2[0]=g2[0].x; f2[1]=g2[0].y; f2[2]=g2[0].z; f2[3]=g2[0].w;             \
        f2[4]=g2[1].x; f2[5]=g2[1].y; f2[6]=g2[1].z; f2[7]=g2[1].w;             \
        f2[8]=g2[2].x; f2[9]=g2[2].y; f2[10]=g2[2].z; f2[11]=g2[2].w;           \
        f2[12]=g2[3].x; f2[13]=g2[3].y; f2[14]=g2[3].z; f2[15]=g2[3].w;         \
        f2[16]=g2[4].x; f2[17]=g2[4].y; f2[18]=g2[4].z; f2[19]=g2[4].w;         \
        _Pragma("unroll")                                                       \
        for (int i = 0; i < 5; ++i) {                                           \
            ushort4 h;                                                          \
            h.x = f2bf(f2[0 + i]);  h.y = f2bf(f2[5 + i]);                      \
            h.z = f2bf(f2[10 + i]); h.w = f2bf(f2[15 + i]);                     \
            *reinterpret_cast<ushort4*>(dst + 512 + (i << 7) + 4 * st) = h;     \
        }                                                                       \
    } while (0)

    // ---- prologue: stage tile b into buf0; issue loads for tile b+G ----
    long tile = blockIdx.x;
    STAGE_LOAD(tile);
    STAGE_WRITE(0);
    if (tile + GRIDSZ < NTILE) STAGE_LOAD(tile + GRIDSZ);
    __syncthreads();

    int cur = 0;
    for (; tile < NTILE; tile += GRIDSZ) {
        // ---- compute from xs[cur]: every B-frag is one ds_read_b128 ----
        f32x4 acc[9];
        #pragma unroll
        for (int q = 0; q < 9; ++q) {
            f32x4 z = {0.f, 0.f, 0.f, 0.f};
            acc[q] = z;
        }

        const unsigned short* row = &xs[cur][lq][0];
        #pragma unroll
        for (int t = 0; t < 4; ++t) {
            const int u0 = 32 * t + lg * 8;
            #pragma unroll
            for (int q = 0; q < 9; ++q) {
                const int s = (q == 0) ? 0 : (q < 4 ? 1 : 2);
                bf16x8 bf = *reinterpret_cast<const bf16x8*>(row + (q << 7) + u0);
                acc[q] = __builtin_amdgcn_mfma_f32_16x16x32_bf16(wf[s][t], bf, acc[q], 0, 0, 0);
            }
        }

        // ---- epilogue: 9 aligned float4 stores (plain; L2 write-combines) ----
        {
            float* orow = out + (tile * NBLK + lq) * (long)DIMF;
            const int vb = v0 + lg * 4;
            float4 o0;
            o0.x = acc[0][0] + biasr[0];
            o0.y = acc[0][1] + biasr[1];
            o0.z = acc[0][2] + biasr[2];
            o0.w = acc[0][3] + biasr[3];
            *reinterpret_cast<float4*>(orow + vb) = o0;
            float* p1 = orow + 128 + 3 * vb;    // 12 consecutive: p=3e+i -> acc[1+p%3][p/3]
            #pragma unroll
            for (int k = 0; k < 3; ++k) {
                float4 o;
                o.x = acc[1 + ((4 * k + 0) % 3)][(4 * k + 0) / 3];
                o.y = acc[1 + ((4 * k + 1) % 3)][(4 * k + 1) / 3];
                o.z = acc[1 + ((4 * k + 2) % 3)][(4 * k + 2) / 3];
                o.w = acc[1 + ((4 * k + 3) % 3)][(4 * k + 3) / 3];
                *reinterpret_cast<float4*>(p1 + 4 * k) = o;
            }
            float* p2 = orow + 512 + 5 * vb;    // 20 consecutive: p=5e+i -> acc[4+p%5][p/5]
            #pragma unroll
            for (int k = 0; k < 5; ++k) {
                float4 o;
                o.x = acc[4 + ((4 * k + 0) % 5)][(4 * k + 0) / 5];
                o.y = acc[4 + ((4 * k + 1) % 5)][(4 * k + 1) / 5];
                o.z = acc[4 + ((4 * k + 2) % 5)][(4 * k + 2) / 5];
                o.w = acc[4 + ((4 * k + 3) % 5)][(4 * k + 3) / 5];
                *reinterpret_cast<float4*>(p2 + 4 * k) = o;
            }
        }

        // ---- retire staged regs into LDS (vmcnt-wait on loads issued a full
        //      period ago -> cheap), then immediately refill them with t+2's
        //      loads so HBM reads stay outstanding across barrier+compute ----
        if (tile + GRIDSZ < NTILE)          STAGE_WRITE(cur ^ 1);
        if (tile + 2 * GRIDSZ < NTILE)      STAGE_LOAD(tile + 2 * GRIDSZ);

        // Relaxed barrier: only LDS ops must drain (lgkmcnt(0)). Global loads
        // and stores keep flowing across it (counted-vmcnt discipline) — a
        // plain __syncthreads() would vmcnt(0)-drain the carried prefetch.
        asm volatile("s_waitcnt lgkmcnt(0)\n\ts_barrier" ::: "memory");
        cur ^= 1;
    }
#undef STAGE_LOAD
#undef STAGE_WRITE
}

extern "C" void kernel_launch(void* const* d_in, const int* in_sizes, int n_in,
                              void* d_out, int out_size, void* d_ws, size_t ws_size,
                              hipStream_t stream) {
    const float* x = (const float*)d_in[0];
    const float* w = (const float*)d_in[1];
    const float* b = (const float*)d_in[2];
    float* outp = (float*)d_out;
    seglin_kernel<<<dim3(GRIDSZ), dim3(512), 0, stream>>>(x, w, b, outp);
}